// Round 8
// baseline (415.622 us; speedup 1.0000x reference)
//
#include <hip/hip_runtime.h>
#include <hip/hip_bf16.h>
#include <stdint.h>

typedef __attribute__((ext_vector_type(8))) short bf16x8;
typedef __attribute__((ext_vector_type(4))) short bf16x4;
typedef __attribute__((ext_vector_type(4))) float f32x4;

__device__ __forceinline__ float b2f(short s) {
  union { unsigned u; float f; } cv;
  cv.u = ((unsigned)(unsigned short)s) << 16;
  return cv.f;
}
__device__ __forceinline__ short f2b(float f) {
  __hip_bfloat16 h = __float2bfloat16(f);
  return *reinterpret_cast<short*>(&h);
}

// Layouts:
//  xT[b][t][c] bf16 (c contiguous, 512/row), per-level elem offsets {0, 8388608, 12582912}.
//  W frags (k-major r = k*512+c): fid = mb*48+kt, lane l: o = mb*16+(l&15), r = kt*32+(l>>4)*8+j.
//  owF1 frags (j-major rr = j*512+c): fid = kt, lane l: k = l&15 (rows>=3 zero),
//    rr = kt*32+(l>>4)*8+j; stored hi = bf16(v), lo = bf16(v - hi).
//  P (layer-1 offset-conv partials): 8 c-groups of 64; per level float bases {0,393216,589824},
//    layout P[g*(24<<tsh) + ((b*3+k)<<tsh) + t].

// ---------- setup: pack W0/W1 frags, owF1 hi/lo frags, mask outputs ----------
__global__ __launch_bounds__(256) void setup_kernel(
    const float* __restrict__ w0, const float* __restrict__ w1,
    __hip_bfloat16* __restrict__ d0, __hip_bfloat16* __restrict__ d1,
    const float* __restrict__ ow1,
    __hip_bfloat16* __restrict__ of1hi, __hip_bfloat16* __restrict__ of1lo,
    const float* __restrict__ m0, const float* __restrict__ m1, const float* __restrict__ m2,
    float* __restrict__ mo) {
  int i = blockIdx.x * 256 + threadIdx.x;
  if (i < 1572864) {
    int l = i >= 786432;
    int i2 = i - (l ? 786432 : 0);
    const float* w = l ? w1 : w0;
    __hip_bfloat16* d = l ? d1 : d0;
    int fid = i2 >> 9, within = i2 & 511, lane = within >> 3, j = within & 7;
    int mb = fid / 48, kt = fid - mb * 48;
    int o = mb * 16 + (lane & 15);
    int r = kt * 32 + (lane >> 4) * 8 + j;
    int k = r >> 9, c = r & 511;
    d[i2] = __float2bfloat16(w[o * 1536 + c * 3 + k]);
  } else if (i < 1597440) {
    int i4 = i - 1572864;
    int fid = i4 >> 9, within = i4 & 511, lane = within >> 3, jj = within & 7;
    int o = lane & 15;
    int rr = fid * 32 + (lane >> 4) * 8 + jj;
    int j = rr >> 9, c = rr & 511;
    float v = (o < 3) ? ow1[o * 1536 + c * 3 + j] : 0.f;
    __hip_bfloat16 hi = __float2bfloat16(v);
    of1hi[i4] = hi;
    of1lo[i4] = __float2bfloat16(v - __bfloat162float(hi));
  } else {
    int i2 = i - 1597440;
    if (i2 < 28672) {
      float v;
      if (i2 < 16384) v = m0[i2];
      else if (i2 < 24576) v = m1[i2 - 16384];
      else v = m2[i2 - 24576];
      mo[i2] = (v != 0.f) ? 1.f : 0.f;
    }
  }
}

// ---------- fused: transpose feats (b,c,t) fp32 -> (b,t,c) bf16 + layer-1 offconv partials ----
// One block per 64c x 64t tile (3584 blocks, levels batched). The staged fp32 tile feeds both
// the bf16 transpose write and a 3-tap conv partial over this block's 64 channels (group g=c0>>6).
__global__ __launch_bounds__(256) void tconv_kernel(const float* __restrict__ x0,
                                                    const float* __restrict__ x1,
                                                    const float* __restrict__ x2,
                                                    const float* __restrict__ ow,
                                                    __hip_bfloat16* __restrict__ xT,
                                                    float* __restrict__ P) {
  __shared__ float fl[64][65];
  __shared__ float fl2[64][2];  // halo columns t0-1, t0+64
  __shared__ float red[3][4][64];
  int f = blockIdx.x;
  int lv = (f < 2048) ? 0 : ((f < 3072) ? 1 : 2);
  int f2 = f - ((lv == 0) ? 0 : ((lv == 1) ? 2048 : 3072));
  int tsh = 11 - lv;
  int T = 1 << tsh;
  const float* x = (lv == 0) ? x0 : ((lv == 1) ? x1 : x2);
  __hip_bfloat16* xo = xT + ((lv == 0) ? 0 : ((lv == 1) ? 8388608 : 12582912));
  float* Pl = P + ((lv == 0) ? 0 : ((lv == 1) ? 393216 : 589824));
  int perb = (1 << (tsh - 6)) * 8;
  int b = f2 / perb;
  int rem = f2 - b * perb;
  int t0 = (rem >> 3) << 6;
  int c0 = (rem & 7) << 6;
  int tid = threadIdx.x;
  int tl = tid & 63, cw = tid >> 6;
  const float* xb = x + ((size_t)(b * 512 + c0) << tsh) + t0;
#pragma unroll
  for (int i = 0; i < 16; ++i) {
    int cl = cw + i * 4;
    fl[cl][tl] = xb[((size_t)cl << tsh) + tl];
  }
  if (tid < 128) {
    int c = tid & 63, side = tid >> 6;
    int tg = side ? (t0 + 64) : (t0 - 1);
    float v = 0.f;
    if ((unsigned)tg < (unsigned)T) v = x[((size_t)(b * 512 + c0 + c) << tsh) + tg];
    fl2[c][side] = v;
  }
  __syncthreads();
  // transpose write
  {
    int tl2 = tid >> 2;
    int cb = (tid & 3) << 4;
    short* orow = (short*)xo + (((size_t)(b << tsh) + t0 + tl2) << 9) + c0 + cb;
#pragma unroll
    for (int h = 0; h < 2; ++h) {
      bf16x8 v;
#pragma unroll
      for (int j = 0; j < 8; ++j) v[j] = f2b(fl[cb + h * 8 + j][tl2]);
      *(bf16x8*)(orow + h * 8) = v;
    }
  }
  // conv partials: thread = (cq = tid>>6 quarter of 16 c, t = tid&63)
  {
    int t = tid & 63, cq = tid >> 6;
    float a0 = 0.f, a1 = 0.f, a2 = 0.f;
#pragma unroll
    for (int c2 = 0; c2 < 16; ++c2) {
      int c = cq * 16 + c2;
      float xm = (t > 0) ? fl[c][t - 1] : fl2[c][0];
      float x0v = fl[c][t];
      float xp = (t < 63) ? fl[c][t + 1] : fl2[c][1];
      const float* wp = ow + (c0 + c) * 3;
      a0 += wp[0] * xm + wp[1] * x0v + wp[2] * xp;
      a1 += wp[1536] * xm + wp[1537] * x0v + wp[1538] * xp;
      a2 += wp[3072] * xm + wp[3073] * x0v + wp[3074] * xp;
    }
    red[0][cq][t] = a0;
    red[1][cq][t] = a1;
    red[2][cq][t] = a2;
  }
  __syncthreads();
  if (tid < 192) {
    int k = tid >> 6, t = tid & 63;
    float s = red[k][0][t] + red[k][1][t] + red[k][2][t] + red[k][3][t];
    Pl[(c0 >> 6) * (24 << tsh) + ((b * 3 + k) << tsh) + t0 + t] = s;
  }
}

// ---------- layer-2 offset conv: skinny MFMA on x1T, ow in hi/lo bf16 ----------
__global__ __launch_bounds__(256, 4) void offconv2_kernel(const __hip_bfloat16* __restrict__ xT,
                                                          const __hip_bfloat16* __restrict__ oHi,
                                                          const __hip_bfloat16* __restrict__ oLo,
                                                          float* __restrict__ offc) {
  int tid = threadIdx.x, lane = tid & 63, wid = tid >> 6;
  int nt = blockIdx.x * 4 + wid;
  int lv = (nt < 1024) ? 0 : ((nt < 1536) ? 1 : 2);
  int ntl = nt - ((lv == 0) ? 0 : ((lv == 1) ? 1024 : 1536));
  int tsh = 11 - lv;
  int T = 1 << tsh;
  const short* xp = (const short*)xT + ((lv == 0) ? 0 : ((lv == 1) ? 8388608 : 12582912));
  float* oc = offc + ((lv == 0) ? 0 : ((lv == 1) ? 49152 : 73728));
  int n = (ntl << 4) + (lane & 15);
  int b = n >> tsh;
  int t = n & (T - 1);
  const short* hip_ = (const short*)oHi + lane * 8;
  const short* lop_ = (const short*)oLo + lane * 8;
  int co = (lane >> 4) << 3;
  f32x4 acc = {};
  for (int kt = 0; kt < 48; ++kt) {
    int j = kt >> 4;
    int c0 = ((kt & 15) << 5) + co;
    int row = t + j - 1;
    bf16x8 bv = {};
    if ((unsigned)row < (unsigned)T)
      bv = *(const bf16x8*)(xp + (((size_t)(b << tsh) + row) << 9) + c0);
    bf16x8 ah = *(const bf16x8*)(hip_ + ((size_t)kt << 9));
    bf16x8 al = *(const bf16x8*)(lop_ + ((size_t)kt << 9));
    acc = __builtin_amdgcn_mfma_f32_16x16x32_bf16(ah, bv, acc, 0, 0, 0);
    acc = __builtin_amdgcn_mfma_f32_16x16x32_bf16(al, bv, acc, 0, 0, 0);
  }
  if ((lane >> 4) == 0) {
#pragma unroll
    for (int r = 0; r < 3; ++r) oc[((b * 3 + r) << tsh) + t] = acc[r];
  }
}

// ---------- fused deform-GEMM, software-pipelined ----------
// grid (448, 2): x = 64-t strip (level-batched), y = m-half (256 rows). 4 waves m-split.
// Per kt: lerp (regs prefetched), ds_write S-frag, lgkm-only barrier (global prefetches for
// kt+1 stay in flight across it), ds_read bv, 16 MFMA with prefetched av.
template <bool LAYER2, bool OUT_BF16>
__global__ __launch_bounds__(256, 3) void dgemm_kernel(
    const __hip_bfloat16* __restrict__ xT, const __hip_bfloat16* __restrict__ Wf,
    const float* __restrict__ off0, const float* __restrict__ off1,
    const float* __restrict__ off2, const float* __restrict__ P8,
    const float* __restrict__ offc2, const float* __restrict__ ob0v,
    const float* __restrict__ ob1v, const float* __restrict__ bias,
    const float* __restrict__ mk0, const float* __restrict__ mk1, const float* __restrict__ mk2,
    void* __restrict__ o0, void* __restrict__ o1, void* __restrict__ o2) {
  __shared__ short sS[2][2048];
  __shared__ float s_f[3][64];
  __shared__ int s_q0[3][64];
  int tid = threadIdx.x, lane = tid & 63, wid = tid >> 6;
  int bx = blockIdx.x;
  int lv = (bx < 256) ? 0 : ((bx < 384) ? 1 : 2);
  int lbx = bx - ((lv == 0) ? 0 : ((lv == 1) ? 256 : 384));
  int tsh = 11 - lv;
  int T = 1 << tsh;
  const short* xp = (const short*)xT + ((lv == 0) ? 0 : ((lv == 1) ? 8388608 : 12582912));
  const float* offin = (lv == 0) ? off0 : ((lv == 1) ? off1 : off2);
  const float* P8l = P8 + ((lv == 0) ? 0 : ((lv == 1) ? 393216 : 589824));
  const float* oc2 = offc2 + ((lv == 0) ? 0 : ((lv == 1) ? 49152 : 73728));
  const float* mask = (lv == 0) ? mk0 : ((lv == 1) ? mk1 : mk2);
  void* outp = (lv == 0) ? o0 : ((lv == 1) ? o1 : o2);
  int nchunk = T >> 6;
  int b = lbx >> (tsh - 6);
  int tb = (lbx & (nchunk - 1)) << 6;
  int mhalf = blockIdx.y;

  if (tid < 192) {
    int k = tid >> 6, tl = tid & 63, t = tb + tl;
    int oi = ((b * 3 + k) << tsh) + t;
    int PT = 24 << tsh;
    float o = offin[oi] + ob0v[k];
#pragma unroll
    for (int g = 0; g < 8; ++g) o += P8l[g * PT + oi];
    if (LAYER2) o += ob1v[k] + oc2[oi];
    float pos = (float)(t + k - 1) + o;
    float pf = floorf(pos);
    s_f[k][tl] = pos - pf;
    s_q0[k][tl] = (int)pf;
  }
  __syncthreads();

  int gtl = (wid << 4) + (lane & 15);
  int q0r[3];
  float fr[3];
  bool ok0[3], ok1[3];
  const short* rp[3];
#pragma unroll
  for (int k = 0; k < 3; ++k) {
    q0r[k] = s_q0[k][gtl];
    fr[k] = s_f[k][gtl];
    ok0[k] = (unsigned)q0r[k] < (unsigned)T;
    ok1[k] = (unsigned)(q0r[k] + 1) < (unsigned)T;
    rp[k] = xp + ((ptrdiff_t)((b << tsh) + q0r[k]) << 9) + ((lane >> 4) << 3);
  }
  const short* wfp = (const short*)Wf + (size_t)(mhalf * 16 + wid * 4) * 48 * 512 + lane * 8;

  f32x4 acc[4][4] = {};
  bf16x8 v0 = {}, v1 = {}, av[4];
  if (ok0[0]) v0 = *(const bf16x8*)rp[0];
  if (ok1[0]) v1 = *(const bf16x8*)(rp[0] + 512);
#pragma unroll
  for (int i = 0; i < 4; ++i) av[i] = *(const bf16x8*)(wfp + ((size_t)(i * 48) << 9));

  int buf = 0;
#pragma unroll
  for (int kt = 0; kt < 48; ++kt) {
    float f = fr[kt >> 4];
    bf16x8 ov;
#pragma unroll
    for (int j = 0; j < 8; ++j) {
      float a = b2f(v0[j]);
      ov[j] = f2b(a + (b2f(v1[j]) - a) * f);
    }
    bf16x8 nv0 = {}, nv1 = {}, nav[4];
    if (kt < 47) {
      int n = kt + 1, k3 = n >> 4, kk = n & 15;
      const short* a = rp[k3] + (kk << 5);
      if (ok0[k3]) nv0 = *(const bf16x8*)a;
      if (ok1[k3]) nv1 = *(const bf16x8*)(a + 512);
#pragma unroll
      for (int i = 0; i < 4; ++i) nav[i] = *(const bf16x8*)(wfp + ((size_t)(i * 48 + n) << 9));
    } else {
#pragma unroll
      for (int i = 0; i < 4; ++i) nav[i] = av[i];
    }
    *(bf16x8*)&sS[buf][(wid << 9) + lane * 8] = ov;
    // LDS-only drain: global prefetches (nv*, nav) stay in flight across the barrier.
    asm volatile("s_waitcnt lgkmcnt(0)\n\ts_barrier" ::: "memory");
    bf16x8 bv[4];
#pragma unroll
    for (int j = 0; j < 4; ++j) bv[j] = *(const bf16x8*)&sS[buf][(j << 9) + lane * 8];
#pragma unroll
    for (int i = 0; i < 4; ++i)
#pragma unroll
      for (int j = 0; j < 4; ++j)
        acc[i][j] = __builtin_amdgcn_mfma_f32_16x16x32_bf16(av[i], bv[j], acc[i][j], 0, 0, 0);
    v0 = nv0;
    v1 = nv1;
#pragma unroll
    for (int i = 0; i < 4; ++i) av[i] = nav[i];
    buf ^= 1;
  }

  // epilogue: D row = (lane>>4)*4 + reg (m), col = lane&15 (t)
  int lrow = lane & 15, lq = lane >> 4;
  int mbase = mhalf * 256 + wid * 64;
  float bvals[4][4];
#pragma unroll
  for (int i = 0; i < 4; ++i)
#pragma unroll
    for (int r = 0; r < 4; ++r) bvals[i][r] = bias[mbase + i * 16 + lq * 4 + r];
#pragma unroll
  for (int j = 0; j < 4; ++j) {
    int col = j * 16 + lrow;
    int t = tb + col;
    float mk = mask[(b << tsh) + t];
    if (OUT_BF16) {
      short* orow = (short*)outp + (((size_t)(b << tsh) + t) << 9);
#pragma unroll
      for (int i = 0; i < 4; ++i) {
        bf16x4 pv;
#pragma unroll
        for (int r = 0; r < 4; ++r)
          pv[r] = f2b(fmaxf(acc[i][j][r] + bvals[i][r], 0.f) * mk);
        *(bf16x4*)(orow + mbase + i * 16 + lq * 4) = pv;
      }
    } else {
#pragma unroll
      for (int i = 0; i < 4; ++i) {
        int m = mbase + i * 16 + lq * 4;
#pragma unroll
        for (int r = 0; r < 4; ++r) {
          float v = fmaxf(acc[i][j][r] + bvals[i][r], 0.f) * mk;
          ((float*)outp)[(((size_t)(b * 512 + m + r)) << tsh) + t] = v;
        }
      }
    }
  }
}

// ---------- launch ----------
extern "C" void kernel_launch(void* const* d_in, const int* in_sizes, int n_in, void* d_out,
                              int out_size, void* d_ws, size_t ws_size, hipStream_t stream) {
  const float* feats[3] = {(const float*)d_in[0], (const float*)d_in[3], (const float*)d_in[6]};
  const float* maskp[3] = {(const float*)d_in[1], (const float*)d_in[4], (const float*)d_in[7]};
  const float* offs[3] = {(const float*)d_in[2], (const float*)d_in[5], (const float*)d_in[8]};
  const float* w[2] = {(const float*)d_in[9], (const float*)d_in[13]};
  const float* bias[2] = {(const float*)d_in[10], (const float*)d_in[14]};
  const float* ow[2] = {(const float*)d_in[11], (const float*)d_in[15]};
  const float* ob[2] = {(const float*)d_in[12], (const float*)d_in[16]};

  const size_t YOFF[3] = {0, 8388608, 12582912};
  const size_t MOFF = 14680064;

  uint8_t* ws = (uint8_t*)d_ws;
  __hip_bfloat16* Wf0 = (__hip_bfloat16*)ws;                 // 1,572,864 B
  __hip_bfloat16* Wf1 = (__hip_bfloat16*)(ws + 1572864);     // 1,572,864 B
  __hip_bfloat16* owF1hi = (__hip_bfloat16*)(ws + 3145728);  // 49,152 B
  __hip_bfloat16* owF1lo = (__hip_bfloat16*)(ws + 3194880);  // 49,152 B
  float* P8 = (float*)(ws + 3244032);                        // 2,752,512 B
  float* offc2 = (float*)(ws + 5996544);                     // 344,064 B
  __hip_bfloat16* fT = (__hip_bfloat16*)(ws + 8388608);      // 29,360,128 B
  __hip_bfloat16* x1T = (__hip_bfloat16*)(ws + 37748736);    // 29,360,128 B (end 64 MiB)

  float* outf = (float*)d_out;

  setup_kernel<<<6448, 256, 0, stream>>>(w[0], w[1], Wf0, Wf1, ow[1], owF1hi, owF1lo,
                                         maskp[0], maskp[1], maskp[2], outf + MOFF);
  tconv_kernel<<<3584, 256, 0, stream>>>(feats[0], feats[1], feats[2], ow[0], fT, P8);

  // layer 1
  dgemm_kernel<false, true><<<dim3(448, 2), 256, 0, stream>>>(
      fT, Wf0, offs[0], offs[1], offs[2], P8, offc2, ob[0], ob[1], bias[0],
      maskp[0], maskp[1], maskp[2], (void*)x1T, (void*)(x1T + YOFF[1]), (void*)(x1T + YOFF[2]));

  // layer 2
  offconv2_kernel<<<448, 256, 0, stream>>>(x1T, owF1hi, owF1lo, offc2);
  dgemm_kernel<true, false><<<dim3(448, 2), 256, 0, stream>>>(
      x1T, Wf1, offs[0], offs[1], offs[2], P8, offc2, ob[0], ob[1], bias[1],
      maskp[0], maskp[1], maskp[2], (void*)(outf + YOFF[0]), (void*)(outf + YOFF[1]),
      (void*)(outf + YOFF[2]));
}